// Round 5
// baseline (104.785 us; speedup 1.0000x reference)
//
#include <hip/hip_runtime.h>
#include <math.h>

typedef __attribute__((ext_vector_type(8))) short bf16x8;
typedef __attribute__((ext_vector_type(4))) short short4v;
typedef __attribute__((ext_vector_type(4))) float f32x4;

#define NB 16
#define NS 720
#define NC 862
#define NP 24
#define NQ 30
#define NDM 128
#define NPRED 336
#define BC (NB*NC)          /* 13792 */
#define SCH 10
#define SLEN 72             /* 720/10 */
#define KP 768              /* padded K: 24 p * 32 q-slots */
#define PBASE (4*BC)        /* stats partials (floats) */
#define WOFF_F (24*BC)      /* float offset of bf16 blobs (16B aligned) */

__device__ __forceinline__ short f2bf(float f) {
    union { float f; unsigned u; } v; v.f = f;
    unsigned r = v.u + 0x7FFFu + ((v.u >> 16) & 1u);   // round-to-nearest-even
    return (short)(r >> 16);
}

// gelu tanh-form: h * sigmoid(2*sqrt(2/pi)*(h + 0.044715 h^3)); |err vs exact| <~2e-4
__device__ __forceinline__ float gelu_f(float h) {
    float hc = fminf(fmaxf(h, -8.f), 8.f);
    float z2 = hc * hc;
    float zz = hc * (0.79788456f + 0.035677408f * z2);   // sqrt(2/pi)*(h+0.044715h^3)
    float e  = __expf(-2.f * zz);
    return h * __builtin_amdgcn_rcpf(1.f + e);
}

// ---------------- stats: two-phase, deterministic ----------------
__global__ __launch_bounds__(256) void stats_partial_k(const float* __restrict__ x,
                                                       float* __restrict__ ws) {
    int b = blockIdx.x, ct = blockIdx.y, ch = blockIdx.z;
    int c = ct * 256 + threadIdx.x;
    if (c >= NC) return;
    const float* xp = x + ((size_t)b * NS + (size_t)ch * SLEN) * NC + c;
    float s = 0.f, sq = 0.f;
    #pragma unroll 4
    for (int i = 0; i < SLEN; ++i) {
        float v = xp[(size_t)i * NC];
        s += v; sq += v * v;
    }
    int idx = b * NC + c;
    float* ps = ws + PBASE;
    ps[(size_t)ch * BC + idx] = s;
    ps[(size_t)(SCH + ch) * BC + idx] = sq;
}

__global__ __launch_bounds__(256) void stats_final_k(float* __restrict__ ws,
                                                     const float* __restrict__ revw,
                                                     const float* __restrict__ revb) {
    int idx = blockIdx.x * 256 + threadIdx.x;
    if (idx >= BC) return;
    const float* ps = ws + PBASE;
    float s = 0.f, sq = 0.f;
    #pragma unroll
    for (int ch = 0; ch < SCH; ++ch) {
        s  += ps[(size_t)ch * BC + idx];
        sq += ps[(size_t)(SCH + ch) * BC + idx];
    }
    int c = idx % NC;
    float mean  = s * (1.f / NS);
    float var   = sq * (1.f / NS) - mean * mean;
    float stdev = sqrtf(var + 1e-5f);
    float rstd  = 1.f / stdev;
    float aw = revw[c] * rstd;
    float u  = stdev / (revw[c] + 1e-10f);
    ws[idx]          = aw;                     // AW
    ws[BC + idx]     = revb[c] - mean * aw;    // BW
    ws[2 * BC + idx] = u;                      // U
    ws[3 * BC + idx] = mean - revb[c] * u;     // V
}

// ---------------- prep: frag-major bf16 weight blobs (direct global MFMA frags) ------
// A-frag layout for 16x16x32: lane l=(lr,lg) holds A[row=lr][k=8*lg+j]; one frag = 1KB.
__global__ __launch_bounds__(256) void wprep_k(const float* __restrict__ W1,
                                               const float* __restrict__ W2,
                                               unsigned short* __restrict__ W1FF,
                                               unsigned short* __restrict__ W2FF) {
    int p = blockIdx.x, tid = threadIdx.x;
    const float* w1 = W1 + (size_t)(NP + p) * NDM * NQ;   // layer 1 only
    const float* w2 = W2 + (size_t)(NP + p) * NQ * NDM;
    #pragma unroll
    for (int pass = 0; pass < 2; ++pass) {
        int s = pass * 256 + tid;                  // 512 frag-lanes per blob
        int l = s & 63, lr = l & 15, lg = l >> 4;
        {   // W1FF[dt][l]: A of H-GEMM, rows=d(dt*16+lr), k=q(8lg+j), dt in [0,8)
            int dt = s >> 6;
            int d = dt * 16 + lr;
            bf16x8 v;
            #pragma unroll
            for (int j = 0; j < 8; ++j) {
                int q = 8 * lg + j;
                v[j] = f2bf(q < NQ ? w1[d * NQ + q] : 0.f);
            }
            ((bf16x8*)(W1FF + (size_t)p * 4096))[s] = v;
        }
        {   // W2FF[mi*4+ks][l]: A of Y-GEMM, rows=q(mi*16+lr), k=d(ks*32+8lg+j)
            int g = s >> 6, mi = g >> 2, ks = g & 3;
            int q = mi * 16 + lr, k = ks * 32 + 8 * lg;
            bf16x8 v;
            #pragma unroll
            for (int j = 0; j < 8; ++j)
                v[j] = f2bf(q < NQ ? w2[q * NDM + k + j] : 0.f);
            ((bf16x8*)(W2FF + (size_t)p * 4096))[s] = v;
        }
    }
}

// PWPF[st][ks][l][j] = pw[m=st*16+lr][k: q=8lg+j, p=ks] (zeros m>=336 or q>=30)
__global__ __launch_bounds__(256) void pwprep_k(const float* __restrict__ pw,
                                                unsigned short* __restrict__ PWPF) {
    int t = blockIdx.x * 256 + threadIdx.x;
    if (t >= 24 * 24 * 64) return;
    int l = t & 63, ks = (t >> 6) % 24, st = t / (24 * 64);
    int lr = l & 15, lg = l >> 4;
    int m = st * 16 + lr;
    bf16x8 v;
    #pragma unroll
    for (int j = 0; j < 8; ++j) {
        int q = 8 * lg + j;
        v[j] = f2bf((m < NPRED && q < NQ) ? pw[(size_t)m * NS + q * NP + ks] : 0.f);
    }
    ((bf16x8*)PWPF)[t] = v;
}

// ---------------- branch: per-p MFMA  H=gelu(W1 Xs); Y = W2 H ----------------
__global__ __launch_bounds__(256) void branch_k(const float* __restrict__ x,
        const unsigned short* __restrict__ W1FF, const unsigned short* __restrict__ W2FF,
        const float* __restrict__ ws, unsigned short* __restrict__ y_t) {
    __shared__ __align__(16) short XsB[4 * 64 * 8];     // B of H-GEMM: rows=c(64), K=q
    __shared__ __align__(16) short HB [16 * 64 * 8];    // B of Y-GEMM: rows=c(64), K=d
    int tid = threadIdx.x;
    int c0 = blockIdx.x * 64;
    int p  = blockIdx.y;
    int b  = blockIdx.z;

    {   // stage Xs: lane=c (coalesced), one 16B LDS write/thread, XOR swizzle
        int c  = tid & 63, kb = tid >> 6;
        int cg = c0 + c;
        bool cv = cg < NC;
        int ce = cv ? cg : NC - 1;
        float aw = ws[b * NC + ce];
        float bw = ws[BC + b * NC + ce];
        const float* xb = x + ((size_t)b * NS + p) * NC + ce;
        bf16x8 v;
        #pragma unroll
        for (int j = 0; j < 8; ++j) {
            int q = kb * 8 + j;
            float val = (q < NQ && cv) ? xb[(size_t)q * NP * NC] * aw + bw : 0.f;
            v[j] = f2bf(val);
        }
        *(bf16x8*)&XsB[(size_t)(kb * 64 + (c ^ kb)) * 8] = v;
    }

    int w = tid >> 6, l = tid & 63, lr = l & 15, lg = l >> 4;
    f32x4 zf = {0.f, 0.f, 0.f, 0.f};
    const bf16x8* w1p = (const bf16x8*)(W1FF + (size_t)p * 4096);
    const bf16x8* w2p = (const bf16x8*)(W2FF + (size_t)p * 4096);
    // A frags direct from global (L2-hot: 224-block reuse per p)
    bf16x8 a0 = w1p[(2 * w) * 64 + l];
    bf16x8 a1 = w1p[(2 * w + 1) * 64 + l];

    __syncthreads();

    // H = W1 @ Xs : M=128(d), N=64(c), K=32. Wave w owns d-tiles {2w,2w+1}.
    f32x4 hc[2][4];
    #pragma unroll
    for (int ni = 0; ni < 4; ++ni) {
        bf16x8 bfr = *(const bf16x8*)&XsB[(size_t)(lg * 64 + ((ni * 16 + lr) ^ lg)) * 8];
        hc[0][ni] = __builtin_amdgcn_mfma_f32_16x16x32_bf16(a0, bfr, zf, 0, 0, 0);
        hc[1][ni] = __builtin_amdgcn_mfma_f32_16x16x32_bf16(a1, bfr, zf, 0, 0, 0);
    }
    // gelu + write H^T into HB (rows=c, K=d), XOR swizzle
    #pragma unroll
    for (int mi2 = 0; mi2 < 2; ++mi2) {
        int d0 = (2 * w + mi2) * 16 + 4 * lg;
        int kb = d0 >> 3, sub = d0 & 7;            // sub in {0,4}
        #pragma unroll
        for (int ni = 0; ni < 4; ++ni) {
            short4v v;
            #pragma unroll
            for (int r = 0; r < 4; ++r)
                v[r] = f2bf(gelu_f(hc[mi2][ni][r]));
            int col = ni * 16 + lr;
            *(short4v*)&HB[(size_t)(kb * 64 + (col ^ kb)) * 8 + sub] = v;
        }
    }
    __syncthreads();

    // Y = W2 @ H : M=32(q), N=64(c), K=128. Wave w owns c-tile w.
    f32x4 yacc[2] = {zf, zf};
    #pragma unroll
    for (int ks = 0; ks < 4; ++ks) {
        int kb = ks * 4 + lg;
        bf16x8 hfr = *(const bf16x8*)&HB[(size_t)(kb * 64 + ((w * 16 + lr) ^ kb)) * 8];
        #pragma unroll
        for (int mi = 0; mi < 2; ++mi) {
            bf16x8 w2f = w2p[(mi * 4 + ks) * 64 + l];
            yacc[mi] = __builtin_amdgcn_mfma_f32_16x16x32_bf16(w2f, hfr, yacc[mi], 0, 0, 0);
        }
    }
    // store: c = w*16+lr; q = mi*16+4lg+r -> one 8B store per mi (zeros fill q>=30)
    int cg2 = c0 + w * 16 + lr;
    if (cg2 < NC) {
        unsigned short* base = y_t + ((size_t)(b * NC + cg2)) * KP + p * 32;
        #pragma unroll
        for (int mi = 0; mi < 2; ++mi) {
            int q0 = mi * 16 + 4 * lg;
            short4v v;
            #pragma unroll
            for (int r = 0; r < 4; ++r)
                v[r] = (q0 + r < NQ) ? f2bf(yacc[mi][r]) : (short)0;
            *(short4v*)(base + q0) = v;
        }
    }
}

// ---------------- projection: 1-wave blocks, m64 x n64 per wave, reg pipeline --------
// __launch_bounds__(64,1): allow the full 2-stage pipeline to live in VGPRs (no
// occupancy-driven load serialization; r4 showed VGPR=56 -> serialized vmcnt waits).
__global__ __launch_bounds__(64, 1) void proj_k(const unsigned short* __restrict__ PWPF,
        const float* __restrict__ pb, const float* __restrict__ ws,
        const unsigned short* __restrict__ y_t, float* __restrict__ out) {
    int l = threadIdx.x;                 // 64 = one wave
    int n0 = blockIdx.x * 64, m0 = blockIdx.y * 64, b = blockIdx.z;
    int lr = l & 15, lg = l >> 4;
    f32x4 zf = {0.f, 0.f, 0.f, 0.f};
    f32x4 acc[4][4];
    #pragma unroll
    for (int mi = 0; mi < 4; ++mi)
        #pragma unroll
        for (int nj = 0; nj < 4; ++nj) acc[mi][nj] = zf;

    const unsigned short* ytb = y_t + (size_t)b * NC * KP;
    const unsigned short* row0;
    const unsigned short* row1;
    const unsigned short* row2;
    const unsigned short* row3;
    {
        int c0 = n0 + 0 * 16 + lr;  if (c0 > NC - 1) c0 = NC - 1;
        int c1 = n0 + 1 * 16 + lr;  if (c1 > NC - 1) c1 = NC - 1;
        int c2 = n0 + 2 * 16 + lr;  if (c2 > NC - 1) c2 = NC - 1;
        int c3 = n0 + 3 * 16 + lr;  if (c3 > NC - 1) c3 = NC - 1;
        row0 = ytb + (size_t)c0 * KP + lg * 8;
        row1 = ytb + (size_t)c1 * KP + lg * 8;
        row2 = ytb + (size_t)c2 * KP + lg * 8;
        row3 = ytb + (size_t)c3 * KP + lg * 8;
    }
    const bf16x8* apb = (const bf16x8*)PWPF + (size_t)(m0 >> 4) * 24 * 64 + l;

    union u16x8 { uint4 u; bf16x8 v; };
    bf16x8 af0[4], af1[4];
    u16x8 b0_[4], b1_[4];

#define LOADF(AF, BF, KS) do {                                       \
        AF[0] = apb[(0 * 24 + (KS)) * 64];                           \
        AF[1] = apb[(1 * 24 + (KS)) * 64];                           \
        AF[2] = apb[(2 * 24 + (KS)) * 64];                           \
        AF[3] = apb[(3 * 24 + (KS)) * 64];                           \
        BF[0].u = *(const uint4*)(row0 + (KS) * 32);                 \
        BF[1].u = *(const uint4*)(row1 + (KS) * 32);                 \
        BF[2].u = *(const uint4*)(row2 + (KS) * 32);                 \
        BF[3].u = *(const uint4*)(row3 + (KS) * 32); } while (0)
#define MM(AF, BF) do {                                              \
        _Pragma("unroll")                                            \
        for (int mi = 0; mi < 4; ++mi) {                             \
            _Pragma("unroll")                                        \
            for (int nj = 0; nj < 4; ++nj)                           \
                acc[mi][nj] = __builtin_amdgcn_mfma_f32_16x16x32_bf16(AF[mi], BF[nj].v, acc[mi][nj], 0, 0, 0); \
        } } while (0)

    LOADF(af0, b0_, 0);
    #pragma unroll
    for (int ks = 0; ks < 24; ks += 2) {
        LOADF(af1, b1_, ks + 1);
        MM(af0, b0_);
        if (ks + 2 < 24) LOADF(af0, b0_, ks + 2);
        MM(af1, b1_);
    }
#undef LOADF
#undef MM

    #pragma unroll
    for (int mi = 0; mi < 4; ++mi) {
        #pragma unroll
        for (int r = 0; r < 4; ++r) {
            int pr = m0 + mi * 16 + 4 * lg + r;
            if (pr >= NPRED) continue;
            float bias = pb[pr];
            #pragma unroll
            for (int nj = 0; nj < 4; ++nj) {
                int c = n0 + nj * 16 + lr;
                if (c >= NC) continue;
                int idx = b * NC + c;
                out[((size_t)b * NPRED + pr) * NC + c] =
                    (acc[mi][nj][r] + bias) * ws[2 * BC + idx] + ws[3 * BC + idx];
            }
        }
    }
}

extern "C" void kernel_launch(void* const* d_in, const int* in_sizes, int n_in,
                              void* d_out, int out_size, void* d_ws, size_t ws_size,
                              hipStream_t stream) {
    const float* x   = (const float*)d_in[0];
    const float* W1  = (const float*)d_in[1];
    const float* W2  = (const float*)d_in[2];
    const float* pw  = (const float*)d_in[3];
    const float* pb  = (const float*)d_in[4];
    const float* rw  = (const float*)d_in[5];
    const float* rb  = (const float*)d_in[6];
    float* out = (float*)d_out;
    float* ws  = (float*)d_ws;
    unsigned short* W1FF = (unsigned short*)(ws + WOFF_F);
    unsigned short* W2FF = W1FF + NP * 4096;
    unsigned short* PWPF = W2FF + NP * 4096;
    unsigned short* y_t  = PWPF + 24 * 24 * 64 * 8;

    stats_partial_k<<<dim3(NB, 4, SCH), 256, 0, stream>>>(x, ws);
    wprep_k<<<dim3(NP), 256, 0, stream>>>(W1, W2, W1FF, W2FF);
    pwprep_k<<<dim3((24 * 24 * 64 + 255) / 256), 256, 0, stream>>>(pw, PWPF);
    stats_final_k<<<dim3((BC + 255) / 256), 256, 0, stream>>>(ws, rw, rb);
    branch_k<<<dim3(14, NP, NB), 256, 0, stream>>>(x, W1FF, W2FF, ws, y_t);
    proj_k<<<dim3(14, 6, NB), 64, 0, stream>>>(PWPF, pb, ws, y_t, out);
}

// Round 6
// 83.648 us; speedup vs baseline: 1.2527x; 1.2527x over previous
//
#include <hip/hip_runtime.h>
#include <math.h>

typedef __attribute__((ext_vector_type(8))) short bf16x8;
typedef __attribute__((ext_vector_type(4))) short short4v;
typedef __attribute__((ext_vector_type(4))) float f32x4;

#define NB 16
#define NS 720
#define NC 862
#define NP 24
#define NQ 30
#define NDM 128
#define NPRED 336
#define BC (NB*NC)          /* 13792 */
#define SCH 10
#define SLEN 72             /* 720/10 */
#define KP 768              /* padded K: 24 p * 32 q-slots */
#define PBASE (4*BC)        /* stats partials (floats) */
#define WOFF_F (24*BC)      /* float offset of bf16 blobs (16B aligned) */
#define NCOL (NB*NC)        /* fused N dimension of proj GEMM = 13792 */

__device__ __forceinline__ short f2bf(float f) {
    union { float f; unsigned u; } v; v.f = f;
    unsigned r = v.u + 0x7FFFu + ((v.u >> 16) & 1u);   // round-to-nearest-even
    return (short)(r >> 16);
}

// gelu tanh-form: h * sigmoid(2*sqrt(2/pi)*(h + 0.044715 h^3)); |err vs exact| <~2e-4
__device__ __forceinline__ float gelu_f(float h) {
    float hc = fminf(fmaxf(h, -8.f), 8.f);
    float z2 = hc * hc;
    float zz = hc * (0.79788456f + 0.035677408f * z2);   // sqrt(2/pi)*(h+0.044715h^3)
    float e  = __expf(-2.f * zz);
    return h * __builtin_amdgcn_rcpf(1.f + e);
}

// async global->LDS, 16B per lane; LDS dest = wave-uniform base + lane*16
__device__ __forceinline__ void gl_lds16(const void* g, void* l) {
    __builtin_amdgcn_global_load_lds(
        (const __attribute__((address_space(1))) unsigned int*)g,
        (__attribute__((address_space(3))) unsigned int*)l, 16, 0, 0);
}

// ---------------- stats: two-phase, deterministic ----------------
__global__ __launch_bounds__(256) void stats_partial_k(const float* __restrict__ x,
                                                       float* __restrict__ ws) {
    int b = blockIdx.x, ct = blockIdx.y, ch = blockIdx.z;
    int c = ct * 256 + threadIdx.x;
    if (c >= NC) return;
    const float* xp = x + ((size_t)b * NS + (size_t)ch * SLEN) * NC + c;
    float s = 0.f, sq = 0.f;
    #pragma unroll 4
    for (int i = 0; i < SLEN; ++i) {
        float v = xp[(size_t)i * NC];
        s += v; sq += v * v;
    }
    int idx = b * NC + c;
    float* ps = ws + PBASE;
    ps[(size_t)ch * BC + idx] = s;
    ps[(size_t)(SCH + ch) * BC + idx] = sq;
}

__global__ __launch_bounds__(256) void stats_final_k(float* __restrict__ ws,
                                                     const float* __restrict__ revw,
                                                     const float* __restrict__ revb) {
    int idx = blockIdx.x * 256 + threadIdx.x;
    if (idx >= BC) return;
    const float* ps = ws + PBASE;
    float s = 0.f, sq = 0.f;
    #pragma unroll
    for (int ch = 0; ch < SCH; ++ch) {
        s  += ps[(size_t)ch * BC + idx];
        sq += ps[(size_t)(SCH + ch) * BC + idx];
    }
    int c = idx % NC;
    float mean  = s * (1.f / NS);
    float var   = sq * (1.f / NS) - mean * mean;
    float stdev = sqrtf(var + 1e-5f);
    float rstd  = 1.f / stdev;
    float aw = revw[c] * rstd;
    float u  = stdev / (revw[c] + 1e-10f);
    ws[idx]          = aw;                     // AW
    ws[BC + idx]     = revb[c] - mean * aw;    // BW
    ws[2 * BC + idx] = u;                      // U
    ws[3 * BC + idx] = mean - revb[c] * u;     // V
}

// ---------------- prep: frag-major bf16 weight blobs (direct global MFMA frags) ------
// A-frag layout for 16x16x32: lane l=(lr,lg) holds A[row=lr][k=8*lg+j]; one frag = 1KB.
__global__ __launch_bounds__(256) void wprep_k(const float* __restrict__ W1,
                                               const float* __restrict__ W2,
                                               unsigned short* __restrict__ W1FF,
                                               unsigned short* __restrict__ W2FF) {
    int p = blockIdx.x, tid = threadIdx.x;
    const float* w1 = W1 + (size_t)(NP + p) * NDM * NQ;   // layer 1 only
    const float* w2 = W2 + (size_t)(NP + p) * NQ * NDM;
    #pragma unroll
    for (int pass = 0; pass < 2; ++pass) {
        int s = pass * 256 + tid;                  // 512 frag-lanes per blob
        int l = s & 63, lr = l & 15, lg = l >> 4;
        {   // W1FF[dt][l]: A of H-GEMM, rows=d(dt*16+lr), k=q(8lg+j), dt in [0,8)
            int dt = s >> 6;
            int d = dt * 16 + lr;
            bf16x8 v;
            #pragma unroll
            for (int j = 0; j < 8; ++j) {
                int q = 8 * lg + j;
                v[j] = f2bf(q < NQ ? w1[d * NQ + q] : 0.f);
            }
            ((bf16x8*)(W1FF + (size_t)p * 4096))[s] = v;
        }
        {   // W2FF[mi*4+ks][l]: A of Y-GEMM, rows=q(mi*16+lr), k=d(ks*32+8lg+j)
            int g = s >> 6, mi = g >> 2, ks = g & 3;
            int q = mi * 16 + lr, k = ks * 32 + 8 * lg;
            bf16x8 v;
            #pragma unroll
            for (int j = 0; j < 8; ++j)
                v[j] = f2bf(q < NQ ? w2[q * NDM + k + j] : 0.f);
            ((bf16x8*)(W2FF + (size_t)p * 4096))[s] = v;
        }
    }
}

// PWPF[st][ks][l][j] = pw[m=st*16+lr][k: q=8lg+j, p=ks] (zeros m>=336 or q>=30)
__global__ __launch_bounds__(256) void pwprep_k(const float* __restrict__ pw,
                                                unsigned short* __restrict__ PWPF) {
    int t = blockIdx.x * 256 + threadIdx.x;
    if (t >= 24 * 24 * 64) return;
    int l = t & 63, ks = (t >> 6) % 24, st = t / (24 * 64);
    int lr = l & 15, lg = l >> 4;
    int m = st * 16 + lr;
    bf16x8 v;
    #pragma unroll
    for (int j = 0; j < 8; ++j) {
        int q = 8 * lg + j;
        v[j] = f2bf((m < NPRED && q < NQ) ? pw[(size_t)m * NS + q * NP + ks] : 0.f);
    }
    ((bf16x8*)PWPF)[t] = v;
}

// ---------------- branch: per-p MFMA  H=gelu(W1 Xs); Y = W2 H ----------------
__global__ __launch_bounds__(256) void branch_k(const float* __restrict__ x,
        const unsigned short* __restrict__ W1FF, const unsigned short* __restrict__ W2FF,
        const float* __restrict__ ws, unsigned short* __restrict__ y_t) {
    __shared__ __align__(16) short XsB[4 * 64 * 8];     // B of H-GEMM: rows=c(64), K=q
    __shared__ __align__(16) short HB [16 * 64 * 8];    // B of Y-GEMM: rows=c(64), K=d
    int tid = threadIdx.x;
    int c0 = blockIdx.x * 64;
    int p  = blockIdx.y;
    int b  = blockIdx.z;

    {   // stage Xs: lane=c (coalesced), one 16B LDS write/thread, XOR swizzle
        int c  = tid & 63, kb = tid >> 6;
        int cg = c0 + c;
        bool cv = cg < NC;
        int ce = cv ? cg : NC - 1;
        float aw = ws[b * NC + ce];
        float bw = ws[BC + b * NC + ce];
        const float* xb = x + ((size_t)b * NS + p) * NC + ce;
        bf16x8 v;
        #pragma unroll
        for (int j = 0; j < 8; ++j) {
            int q = kb * 8 + j;
            float val = (q < NQ && cv) ? xb[(size_t)q * NP * NC] * aw + bw : 0.f;
            v[j] = f2bf(val);
        }
        *(bf16x8*)&XsB[(size_t)(kb * 64 + (c ^ kb)) * 8] = v;
    }

    int w = tid >> 6, l = tid & 63, lr = l & 15, lg = l >> 4;
    f32x4 zf = {0.f, 0.f, 0.f, 0.f};
    const bf16x8* w1p = (const bf16x8*)(W1FF + (size_t)p * 4096);
    const bf16x8* w2p = (const bf16x8*)(W2FF + (size_t)p * 4096);
    // A frags direct from global (L2-hot: 224-block reuse per p)
    bf16x8 a0 = w1p[(2 * w) * 64 + l];
    bf16x8 a1 = w1p[(2 * w + 1) * 64 + l];

    __syncthreads();

    // H = W1 @ Xs : M=128(d), N=64(c), K=32. Wave w owns d-tiles {2w,2w+1}.
    f32x4 hc[2][4];
    #pragma unroll
    for (int ni = 0; ni < 4; ++ni) {
        bf16x8 bfr = *(const bf16x8*)&XsB[(size_t)(lg * 64 + ((ni * 16 + lr) ^ lg)) * 8];
        hc[0][ni] = __builtin_amdgcn_mfma_f32_16x16x32_bf16(a0, bfr, zf, 0, 0, 0);
        hc[1][ni] = __builtin_amdgcn_mfma_f32_16x16x32_bf16(a1, bfr, zf, 0, 0, 0);
    }
    // gelu + write H^T into HB (rows=c, K=d), XOR swizzle
    #pragma unroll
    for (int mi2 = 0; mi2 < 2; ++mi2) {
        int d0 = (2 * w + mi2) * 16 + 4 * lg;
        int kb = d0 >> 3, sub = d0 & 7;            // sub in {0,4}
        #pragma unroll
        for (int ni = 0; ni < 4; ++ni) {
            short4v v;
            #pragma unroll
            for (int r = 0; r < 4; ++r)
                v[r] = f2bf(gelu_f(hc[mi2][ni][r]));
            int col = ni * 16 + lr;
            *(short4v*)&HB[(size_t)(kb * 64 + (col ^ kb)) * 8 + sub] = v;
        }
    }
    __syncthreads();

    // Y = W2 @ H : M=32(q), N=64(c), K=128. Wave w owns c-tile w.
    f32x4 yacc[2] = {zf, zf};
    #pragma unroll
    for (int ks = 0; ks < 4; ++ks) {
        int kb = ks * 4 + lg;
        bf16x8 hfr = *(const bf16x8*)&HB[(size_t)(kb * 64 + ((w * 16 + lr) ^ kb)) * 8];
        #pragma unroll
        for (int mi = 0; mi < 2; ++mi) {
            bf16x8 w2f = w2p[(mi * 4 + ks) * 64 + l];
            yacc[mi] = __builtin_amdgcn_mfma_f32_16x16x32_bf16(w2f, hfr, yacc[mi], 0, 0, 0);
        }
    }
    // store: c = w*16+lr; q = mi*16+4lg+r -> one 8B store per mi (zeros fill q>=30)
    int cg2 = c0 + w * 16 + lr;
    if (cg2 < NC) {
        unsigned short* base = y_t + ((size_t)(b * NC + cg2)) * KP + p * 32;
        #pragma unroll
        for (int mi = 0; mi < 2; ++mi) {
            int q0 = mi * 16 + 4 * lg;
            short4v v;
            #pragma unroll
            for (int r = 0; r < 4; ++r)
                v[r] = (q0 + r < NQ) ? f2bf(yacc[mi][r]) : (short)0;
            *(short4v*)(base + q0) = v;
        }
    }
}

// ---------------- projection v3: one fused GEMM M=384, N=13792 (b,c), K=768 ----------
// m97-pattern: global_load_lds staging + LDS double-buffer + 1 barrier per K-step.
// Block: 4 waves, tile m64 x n128. Wave w: A-frags mi=0..3 (shared), B-frags {2w,2w+1}.
// LDS per buffer: 4 A-frags + 8 B-frags, 1KB each (linear frag-major, lane*16B slots).
__global__ __launch_bounds__(256, 4) void proj_k(const unsigned short* __restrict__ PWPF,
        const float* __restrict__ pb, const float* __restrict__ ws,
        const unsigned short* __restrict__ y_t, float* __restrict__ out) {
    __shared__ __align__(16) short L[2][12 * 512];
    int tid = threadIdx.x;
    int w = tid >> 6, l = tid & 63, lr = l & 15, lg = l >> 4;
    int gn0 = blockIdx.x * 128;          // fused col base (n = b*NC + c)
    int m0  = blockIdx.y * 64;           // pr base
    f32x4 zf = {0.f, 0.f, 0.f, 0.f};
    f32x4 acc[4][2];
    #pragma unroll
    for (int mi = 0; mi < 4; ++mi) { acc[mi][0] = zf; acc[mi][1] = zf; }

    // staging sources (per-lane addresses; LDS dest is wave-uniform)
    int cgA = gn0 + (2 * w) * 16 + lr;      if (cgA > NCOL - 1) cgA = NCOL - 1;
    int cgB = gn0 + (2 * w + 1) * 16 + lr;  if (cgB > NCOL - 1) cgB = NCOL - 1;
    const unsigned short* bsrcA = y_t + (size_t)cgA * KP + lg * 8;
    const unsigned short* bsrcB = y_t + (size_t)cgB * KP + lg * 8;
    const unsigned short* asrc  = PWPF + ((size_t)(m0 / 16 + w) * 24) * 512 + (size_t)l * 8;

#define STAGE(BUF, KS) do {                                              \
        gl_lds16(asrc  + (size_t)(KS) * 512, &L[BUF][w * 512]);          \
        gl_lds16(bsrcA + (size_t)(KS) * 32,  &L[BUF][(4 + 2 * w) * 512]);\
        gl_lds16(bsrcB + (size_t)(KS) * 32,  &L[BUF][(5 + 2 * w) * 512]);\
    } while (0)

    STAGE(0, 0);
    __syncthreads();                      // drains vmcnt(0) lgkmcnt(0) + barrier
    int cur = 0;
    for (int ks = 0; ks < 24; ++ks) {
        if (ks + 1 < 24) STAGE(cur ^ 1, ks + 1);
        const short* Lc = &L[cur][0];
        bf16x8 b0 = *(const bf16x8*)&Lc[(4 + 2 * w) * 512 + l * 8];
        bf16x8 b1 = *(const bf16x8*)&Lc[(5 + 2 * w) * 512 + l * 8];
        #pragma unroll
        for (int mi = 0; mi < 4; ++mi) {
            bf16x8 a = *(const bf16x8*)&Lc[mi * 512 + l * 8];
            acc[mi][0] = __builtin_amdgcn_mfma_f32_16x16x32_bf16(a, b0, acc[mi][0], 0, 0, 0);
            acc[mi][1] = __builtin_amdgcn_mfma_f32_16x16x32_bf16(a, b1, acc[mi][1], 0, 0, 0);
        }
        __syncthreads();
        cur ^= 1;
    }
#undef STAGE

    #pragma unroll
    for (int mi = 0; mi < 4; ++mi) {
        #pragma unroll
        for (int r = 0; r < 4; ++r) {
            int pr = m0 + mi * 16 + 4 * lg + r;
            if (pr >= NPRED) continue;
            float bias = pb[pr];
            #pragma unroll
            for (int nj = 0; nj < 2; ++nj) {
                int cg = gn0 + (2 * w + nj) * 16 + lr;
                if (cg >= NCOL) continue;
                int bb = cg / NC;
                int cc = cg - bb * NC;
                out[((size_t)bb * NPRED + pr) * NC + cc] =
                    (acc[mi][nj][r] + bias) * ws[2 * BC + cg] + ws[3 * BC + cg];
            }
        }
    }
}

extern "C" void kernel_launch(void* const* d_in, const int* in_sizes, int n_in,
                              void* d_out, int out_size, void* d_ws, size_t ws_size,
                              hipStream_t stream) {
    const float* x   = (const float*)d_in[0];
    const float* W1  = (const float*)d_in[1];
    const float* W2  = (const float*)d_in[2];
    const float* pw  = (const float*)d_in[3];
    const float* pb  = (const float*)d_in[4];
    const float* rw  = (const float*)d_in[5];
    const float* rb  = (const float*)d_in[6];
    float* out = (float*)d_out;
    float* ws  = (float*)d_ws;
    unsigned short* W1FF = (unsigned short*)(ws + WOFF_F);
    unsigned short* W2FF = W1FF + NP * 4096;
    unsigned short* PWPF = W2FF + NP * 4096;
    unsigned short* y_t  = PWPF + 24 * 24 * 64 * 8;

    stats_partial_k<<<dim3(NB, 4, SCH), 256, 0, stream>>>(x, ws);
    wprep_k<<<dim3(NP), 256, 0, stream>>>(W1, W2, W1FF, W2FF);
    pwprep_k<<<dim3((24 * 24 * 64 + 255) / 256), 256, 0, stream>>>(pw, PWPF);
    stats_final_k<<<dim3((BC + 255) / 256), 256, 0, stream>>>(ws, rw, rb);
    branch_k<<<dim3(14, NP, NB), 256, 0, stream>>>(x, W1FF, W2FF, ws, y_t);
    proj_k<<<dim3((NCOL + 127) / 128, 6), 256, 0, stream>>>(PWPF, pb, ws, y_t, out);
}